// Round 2
// baseline (234.001 us; speedup 1.0000x reference)
//
#include <hip/hip_runtime.h>
#include <cstdint>
#include <cmath>

#define SEQ 1024
#define BATCH 8
#define NK 4

// ---------------------------------------------------------------------------
// Kernel A: factA4[b,i] = 0.7 if exists p<i with any_k rel[b,i,p,k] > 0.5 else 1.0
// (exists_earlier implies maxrel>0.5, so maxrel is never needed.)
// ONE 64-lane wave per (b,i) row, wave-level __any, early exit. Each probe
// reads 64 float4 = 1 KB; with uniform(0,1) data P(no hit in 256 samples) ~ 0,
// so expected fetch ~ 1 KB/row -> ~8 MB total.
// ---------------------------------------------------------------------------
__global__ __launch_bounds__(256) void krelA(const float* __restrict__ rel,
                                             float* __restrict__ factA4) {
    int row  = blockIdx.x * 4 + (threadIdx.x >> 6);   // b*SEQ + i, one wave per row
    int lane = threadIdx.x & 63;
    int i = row & (SEQ - 1);
    const float4* row4 = reinterpret_cast<const float4*>(rel) + (size_t)row * SEQ;
    bool found = false;
    for (int base = 0; base < i; base += 64) {
        int p = base + lane;
        bool pred = false;
        if (p < i) {
            float4 v = row4[p];
            pred = (v.x > 0.5f) | (v.y > 0.5f) | (v.z > 0.5f) | (v.w > 0.5f);
        }
        if (__any((int)pred)) { found = true; break; }
    }
    if (lane == 0) factA4[row] = found ? 0.7f : 1.0f;
}

// ---------------------------------------------------------------------------
// Fused kernel: one block per batch, 1024 threads (one per seq position).
// Phase 1 (per thread, registers only): consistency-MLP mult1, softmax-top2
//   implicit flags, window-3 explicit flags, faf/fof, and 3 activity bits:
//     A = act of updated row if isolated (fact3=0.1)
//     N = act of updated row if not     (fact3=1.0)   [A implies N]
//     O = act of ORIGINAL row
// Phase 2: ballot bits into LDS (16x u64), thread 0 runs the boolean
//   recurrence  u[i] = A[i] | (N[i] & (u[i-1]|u[i-2]|O[i+1]|O[i+2]))
//   with iso[i] = !(u[i-1]|u[i-2]|O[i+1]|O[i+2]).
// Phase 3: every thread applies its factors (all still in registers) and
//   writes both outputs.
// ---------------------------------------------------------------------------
__global__ __launch_bounds__(1024) void kfused(
    const float4* __restrict__ aL4, const float4* __restrict__ oL4,
    const int* __restrict__ exA, const int* __restrict__ exO,
    const float* __restrict__ W1, const float* __restrict__ b1,
    const float* __restrict__ W2, const float* __restrict__ b2,
    const float* __restrict__ W3, const float* __restrict__ b3,
    const float* __restrict__ factA4,
    float4* __restrict__ outA4, float4* __restrict__ outO4) {
    int b = blockIdx.x;
    int pos = threadIdx.x;                 // 0..1023
    int gid = b * SEQ + pos;

    __shared__ unsigned long long A64[16], N64[16], O64[16], ISO[16];

    float4 a = aL4[gid], o = oL4[gid];
    float x[8] = {a.x, a.y, a.z, a.w, o.x, o.y, o.z, o.w};

    // MLP 8 -> 32 -> 16 -> 1, relu, relu, sigmoid
    float h1[32];
#pragma unroll
    for (int j = 0; j < 32; ++j) h1[j] = b1[j];
#pragma unroll
    for (int k = 0; k < 8; ++k)
#pragma unroll
        for (int j = 0; j < 32; ++j) h1[j] = fmaf(x[k], W1[k * 32 + j], h1[j]);
#pragma unroll
    for (int j = 0; j < 32; ++j) h1[j] = fmaxf(h1[j], 0.0f);

    float h2[16];
#pragma unroll
    for (int j = 0; j < 16; ++j) h2[j] = b2[j];
#pragma unroll
    for (int k = 0; k < 32; ++k)
#pragma unroll
        for (int j = 0; j < 16; ++j) h2[j] = fmaf(h1[k], W2[k * 16 + j], h2[j]);
#pragma unroll
    for (int j = 0; j < 16; ++j) h2[j] = fmaxf(h2[j], 0.0f);

    float z = b3[0];
#pragma unroll
    for (int k = 0; k < 16; ++k) z = fmaf(h2[k], W3[k], z);
    float c = 1.0f / (1.0f + expf(-z));
    float m1 = (c < 0.5f) ? (2.0f * c) : 1.0f;

    // softmax top-2 fractions
    float ma = fmaxf(fmaxf(a.x, a.y), fmaxf(a.z, a.w));
    float ea0 = expf(a.x - ma), ea1 = expf(a.y - ma), ea2 = expf(a.z - ma), ea3 = expf(a.w - ma);
    bool impA = (ea0 + ea1) / (ea0 + ea1 + ea2 + ea3) > 0.5f;
    float mo = fmaxf(fmaxf(o.x, o.y), fmaxf(o.z, o.w));
    float eo0 = expf(o.x - mo), eo1 = expf(o.y - mo), eo2 = expf(o.z - mo), eo3 = expf(o.w - mo);
    bool impO = (eo0 + eo1) / (eo0 + eo1 + eo2 + eo3) > 0.5f;

    // window-3 any of explicit flags
    bool nearA = false, nearO = false;
#pragma unroll
    for (int d = -3; d <= 3; ++d) {
        int j = pos + d;
        if (j >= 0 && j < SEQ) {
            nearA |= exA[b * SEQ + j] > 0;
            nearO |= exO[b * SEQ + j] > 0;
        }
    }
    float fA2 = (impA && !nearO) ? 0.3f : 1.0f;
    float fO2 = (impO && !nearA) ? 0.3f : 1.0f;
    float faf = fA2 * factA4[gid];   // fixed part of fa (fact3 applied later)
    float fof = fO2;

    // activity bits
    float a01 = fmaxf(a.x, a.y) * m1, a23 = fmaxf(a.z, a.w) * m1;
    float o01 = fmaxf(o.x, o.y) * m1, o23 = fmaxf(o.z, o.w) * m1;
    bool actNon = (fmaxf(a01 * faf, a23) > 0.5f) || (fmaxf(o01 * fof, o23) > 0.5f);
    bool actIso = (fmaxf(a01 * faf * 0.1f, a23) > 0.5f) || (fmaxf(o01 * fof * 0.1f, o23) > 0.5f);
    bool actOrig = (ma > 0.5f) || (mo > 0.5f);

    unsigned long long bA = __ballot((int)actIso);
    unsigned long long bN = __ballot((int)actNon);
    unsigned long long bO = __ballot((int)actOrig);
    int w = pos >> 6;
    if ((pos & 63) == 0) { A64[w] = bA; N64[w] = bN; O64[w] = bO; }
    __syncthreads();

    if (pos == 0) {
        unsigned int u1 = 0, u2 = 0;   // u[i-1], u[i-2]
        for (int wi = 0; wi < 16; ++wi) {
            unsigned long long aw = A64[wi], nw = N64[wi];
            unsigned long long ow = O64[wi];
            unsigned long long on = (wi < 15) ? O64[wi + 1] : 0ull;
            // ro[j] = O[pos+1] | O[pos+2]
            unsigned long long rw = ((ow >> 1) | (on << 63)) | ((ow >> 2) | (on << 62));
            unsigned long long isoW = 0;
#pragma unroll
            for (int j = 0; j < 64; ++j) {
                unsigned int ro = (unsigned int)(rw >> j) & 1u;
                unsigned int t  = u1 | u2 | ro;
                unsigned int ab = (unsigned int)(aw >> j) & 1u;
                unsigned int nb = (unsigned int)(nw >> j) & 1u;
                unsigned int u  = ab | (nb & t);
                isoW |= (unsigned long long)(t ^ 1u) << j;
                u2 = u1; u1 = u;
            }
            ISO[wi] = isoW;
        }
    }
    __syncthreads();

    unsigned int iso = (unsigned int)(ISO[pos >> 6] >> (pos & 63)) & 1u;
    float f3 = iso ? 0.1f : 1.0f;
    float fa = faf * f3;
    float fo = fof * f3;
    outA4[gid] = make_float4(a.x * m1 * fa, a.y * m1 * fa, a.z * m1, a.w * m1);
    outO4[gid] = make_float4(o.x * m1 * fo, o.y * m1 * fo, o.z * m1, o.w * m1);
}

extern "C" void kernel_launch(void* const* d_in, const int* in_sizes, int n_in,
                              void* d_out, int out_size, void* d_ws, size_t ws_size,
                              hipStream_t stream) {
    const float* aL  = (const float*)d_in[0];
    const float* oL  = (const float*)d_in[1];
    const float* rel = (const float*)d_in[2];
    const int*   exA = (const int*)d_in[3];
    const int*   exO = (const int*)d_in[4];
    const float* W1 = (const float*)d_in[5];
    const float* b1 = (const float*)d_in[6];
    const float* W2 = (const float*)d_in[7];
    const float* b2 = (const float*)d_in[8];
    const float* W3 = (const float*)d_in[9];
    const float* b3 = (const float*)d_in[10];

    float* factA4 = (float*)d_ws;       // 8192 floats
    float* out = (float*)d_out;         // [cA (32768 floats) | cO (32768 floats)]

    krelA<<<(BATCH * SEQ) / 4, 256, 0, stream>>>(rel, factA4);
    kfused<<<BATCH, 1024, 0, stream>>>(
        (const float4*)aL, (const float4*)oL, exA, exO,
        W1, b1, W2, b2, W3, b3, factA4,
        (float4*)out, (float4*)(out + (size_t)BATCH * SEQ * NK));
}